// Round 1
// baseline (774.443 us; speedup 1.0000x reference)
//
#include <hip/hip_runtime.h>

#define PAD   4
#define DD    9          // displacements per axis
#define ND    81
#define BB    4
#define CCH   256
#define HH_   128
#define WW_   224
#define TH    8
#define TW    32
#define CCS   8          // channels staged per iteration
#define SH    (TH + 2*PAD)   // 16
#define SW    (TW + 2*PAD)   // 40
#define NTHREADS 576     // 9 waves: wave i handles dy=i

__global__ __launch_bounds__(NTHREADS)
void corr_kernel(const float* __restrict__ first,
                 const float* __restrict__ second,
                 float* __restrict__ out)
{
    __shared__ float fS[CCS][TH][TW];   // 8 KB
    __shared__ float sS[CCS][SH][SW];   // 20 KB

    const int wt = blockIdx.x;          // 0..6
    const int ht = blockIdx.y;          // 0..15
    const int b  = blockIdx.z;          // 0..3
    const int w0 = wt * TW;
    const int h0 = ht * TH;

    const int t    = threadIdx.x;
    const int dy   = t >> 6;            // wave index = dy group, 0..8
    const int lane = t & 63;
    const int wq   = lane & 7;          // 0..7 -> cols wq*4 .. wq*4+3
    const int hh   = lane >> 3;         // 0..7 -> row hh

    const size_t plane  = (size_t)HH_ * WW_;
    const float* fbase = first  + (size_t)b * CCH * plane;
    const float* sbase = second + (size_t)b * CCH * plane;

    float acc[DD][4];
    #pragma unroll
    for (int dx = 0; dx < DD; ++dx)
        #pragma unroll
        for (int px = 0; px < 4; ++px) acc[dx][px] = 0.f;

    for (int c0 = 0; c0 < CCH; c0 += CCS) {
        __syncthreads();   // protect LDS from previous iteration's readers
        // ---- stage first tile: CCS*TH*TW = 2048 elements ----
        for (int idx = t; idx < CCS*TH*TW; idx += NTHREADS) {
            int cc  = idx / (TH*TW);
            int r   = (idx / TW) & (TH-1);
            int col = idx & (TW-1);
            fS[cc][r][col] = fbase[(size_t)(c0+cc)*plane + (size_t)(h0+r)*WW_ + (w0+col)];
        }
        // ---- stage second tile with halo: CCS*SH*SW = 5120 elements ----
        for (int idx = t; idx < CCS*SH*SW; idx += NTHREADS) {
            int cc  = idx / (SH*SW);
            int rem = idx % (SH*SW);
            int r   = rem / SW;
            int col = rem % SW;
            int gh  = h0 + r - PAD;
            int gw  = w0 + col - PAD;
            float v = 0.f;
            if (gh >= 0 && gh < HH_ && gw >= 0 && gw < WW_)
                v = sbase[(size_t)(c0+cc)*plane + (size_t)gh*WW_ + gw];
            sS[cc][r][col] = v;
        }
        __syncthreads();

        // ---- compute: per channel 4x ds_read_b128 + 36 FMA ----
        #pragma unroll
        for (int cc = 0; cc < CCS; ++cc) {
            float4 f4 = *(const float4*)&fS[cc][hh][wq*4];
            const float* srow = &sS[cc][hh + dy][wq*4];
            float4 sA = *(const float4*)(srow + 0);
            float4 sB = *(const float4*)(srow + 4);
            float4 sC = *(const float4*)(srow + 8);
            float f[4]  = {f4.x, f4.y, f4.z, f4.w};
            float s[12] = {sA.x, sA.y, sA.z, sA.w,
                           sB.x, sB.y, sB.z, sB.w,
                           sC.x, sC.y, sC.z, sC.w};
            #pragma unroll
            for (int dx = 0; dx < DD; ++dx)
                #pragma unroll
                for (int px = 0; px < 4; ++px)
                    acc[dx][px] += f[px] * s[dx + px];
        }
    }

    // ---- epilogue: 9 float4 stores, scale by 1/C (exact pow2) ----
    const float inv = 1.0f / (float)CCH;
    const int h = h0 + hh;
    const int w = w0 + wq*4;
    #pragma unroll
    for (int dx = 0; dx < DD; ++dx) {
        int d = dy*DD + dx;
        float4 o;
        o.x = acc[dx][0]*inv; o.y = acc[dx][1]*inv;
        o.z = acc[dx][2]*inv; o.w = acc[dx][3]*inv;
        *(float4*)&out[(((size_t)b*ND + d)*HH_ + h)*WW_ + w] = o;
    }
}

extern "C" void kernel_launch(void* const* d_in, const int* in_sizes, int n_in,
                              void* d_out, int out_size, void* d_ws, size_t ws_size,
                              hipStream_t stream) {
    const float* first  = (const float*)d_in[0];
    const float* second = (const float*)d_in[1];
    float* out = (float*)d_out;
    dim3 grid(WW_ / TW, HH_ / TH, BB);   // (7, 16, 4)
    dim3 block(NTHREADS);
    corr_kernel<<<grid, block, 0, stream>>>(first, second, out);
}

// Round 2
// 764.880 us; speedup vs baseline: 1.0125x; 1.0125x over previous
//
#include <hip/hip_runtime.h>

#define PAD   4
#define DD    9
#define ND    81
#define BB    4
#define CCH   256
#define HH_   128
#define WW_   224
#define TH    8
#define TW    32
#define CCS   4                  // channels per LDS chunk
#define NCHUNK (CCH/CCS)         // 64
#define SH    16                 // TH + 2*PAD
#define SW    48                 // padded row stride (valid cols 0..39)
#define NTHREADS 576             // 9 waves, wave i = dy i
#define NQUAD (CCS*SH*10)        // 640 float4 staging slots per chunk

__global__ __launch_bounds__(NTHREADS, 5)
void corr_kernel(const float* __restrict__ first,
                 const float* __restrict__ second,
                 float* __restrict__ out)
{
    __shared__ float sS[2][CCS][SH][SW];   // 2 x 12 KB = 24 KB

    const int wt = blockIdx.x, ht = blockIdx.y, b = blockIdx.z;
    const int w0 = wt * TW, h0 = ht * TH;
    const int t = threadIdx.x;
    const int dy   = t >> 6;               // wave = dy
    const int lane = t & 63;
    const int wq   = lane & 7;             // column quad -> cols wq*4..+3
    const int hh   = lane >> 3;            // row 0..7

    const size_t plane = (size_t)HH_ * WW_;
    const size_t cstep = (size_t)CCS * plane;

    // ---- staging assignment: constant per thread, no per-iter div/mod ----
    // slot idx -> cc = idx/160, r = (idx%160)/10, q = idx%10 (10 quads = 40 cols)
    const int idx0 = t;                               // always < 640
    const int cc0 = idx0/160, r0 = (idx0%160)/10, q0 = idx0%10;
    const int gh0 = h0 - PAD + r0, gw0 = w0 - PAD + 4*q0;
    const bool p0 = (gh0 >= 0 && gh0 < HH_ && gw0 >= 0 && gw0 < WW_);
    const float* sp0 = second + ((size_t)b*CCH + cc0)*plane + (size_t)gh0*WW_ + gw0;
    const int lo0 = (cc0*SH + r0)*SW + 4*q0;

    const int idx1 = t + NTHREADS;                    // valid iff < 640 (t < 64)
    const bool v1 = (idx1 < NQUAD);
    const int cc1 = idx1/160, r1 = (idx1%160)/10, q1 = idx1%10;
    const int gh1 = h0 - PAD + r1, gw1 = w0 - PAD + 4*q1;
    const bool p1 = v1 && (gh1 >= 0 && gh1 < HH_ && gw1 >= 0 && gw1 < WW_);
    const float* sp1 = second + ((size_t)b*CCH + cc1)*plane + (size_t)gh1*WW_ + gw1;
    const int lo1 = (cc1*SH + r1)*SW + 4*q1;

    const float* fptr = first + (size_t)b*CCH*plane + (size_t)(h0+hh)*WW_ + (w0 + wq*4);

    const float4 z4 = make_float4(0.f, 0.f, 0.f, 0.f);

    // ---- prologue: stage chunk 0 into buffer 0 ----
    {
        float4 s0 = p0 ? *(const float4*)sp0 : z4;
        float4 s1 = p1 ? *(const float4*)sp1 : z4;
        float* wbuf = &sS[0][0][0][0];
        *(float4*)(wbuf + lo0) = s0;
        if (v1) *(float4*)(wbuf + lo1) = s1;
    }
    sp0 += cstep; sp1 += cstep;
    __syncthreads();

    float acc[DD][4];
    #pragma unroll
    for (int dx = 0; dx < DD; ++dx) { acc[dx][0]=0.f; acc[dx][1]=0.f; acc[dx][2]=0.f; acc[dx][3]=0.f; }

    const int rowoff = (hh + dy)*SW + wq*4;

    for (int k = 0; k < NCHUNK; ++k) {
        const int cur = k & 1, nxt = cur ^ 1;
        const bool last = (k == NCHUNK-1);

        // issue next chunk's second-tile loads before compute (latency overlap)
        float4 n0 = z4, n1 = z4;
        if (!last) {
            n0 = p0 ? *(const float4*)sp0 : z4;
            n1 = p1 ? *(const float4*)sp1 : z4;
            sp0 += cstep; sp1 += cstep;
        }

        // first tile: straight from global into registers (each quad private)
        float4 fc[CCS];
        #pragma unroll
        for (int c = 0; c < CCS; ++c) fc[c] = *(const float4*)(fptr + c*plane);
        fptr += cstep;

        const float* sbuf = &sS[cur][0][0][0];
        #pragma unroll
        for (int c = 0; c < CCS; ++c) {
            const float* srow = sbuf + c*(SH*SW) + rowoff;
            float4 sA = *(const float4*)(srow);
            float4 sB = *(const float4*)(srow + 4);
            float4 sC = *(const float4*)(srow + 8);
            float s[12] = {sA.x,sA.y,sA.z,sA.w, sB.x,sB.y,sB.z,sB.w, sC.x,sC.y,sC.z,sC.w};
            float f[4]  = {fc[c].x, fc[c].y, fc[c].z, fc[c].w};
            #pragma unroll
            for (int dx = 0; dx < DD; ++dx)
                #pragma unroll
                for (int px = 0; px < 4; ++px)
                    acc[dx][px] += f[px] * s[dx + px];
        }

        if (!last) {
            __syncthreads();   // all reads of sS[nxt] (chunk k-1) complete
            float* wbuf = &sS[nxt][0][0][0];
            *(float4*)(wbuf + lo0) = n0;
            if (v1) *(float4*)(wbuf + lo1) = n1;
            __syncthreads();   // writes visible before next compute
        }
    }

    // ---- epilogue ----
    const float inv = 1.0f / (float)CCH;
    const int h = h0 + hh, w = w0 + wq*4;
    #pragma unroll
    for (int dx = 0; dx < DD; ++dx) {
        const int d = dy*DD + dx;
        float4 o = make_float4(acc[dx][0]*inv, acc[dx][1]*inv,
                               acc[dx][2]*inv, acc[dx][3]*inv);
        *(float4*)&out[(((size_t)b*ND + d)*HH_ + h)*WW_ + w] = o;
    }
}

extern "C" void kernel_launch(void* const* d_in, const int* in_sizes, int n_in,
                              void* d_out, int out_size, void* d_ws, size_t ws_size,
                              hipStream_t stream) {
    const float* first  = (const float*)d_in[0];
    const float* second = (const float*)d_in[1];
    float* out = (float*)d_out;
    dim3 grid(WW_ / TW, HH_ / TH, BB);   // (7, 16, 4)
    dim3 block(NTHREADS);
    corr_kernel<<<grid, block, 0, stream>>>(first, second, out);
}

// Round 3
// 463.148 us; speedup vs baseline: 1.6721x; 1.6515x over previous
//
#include <hip/hip_runtime.h>

#define PAD   4
#define DD    9
#define ND    81
#define BB    4
#define CCH   256
#define HH_   128
#define WW_   224
#define TH    8
#define TW    32
#define NTILES 448               // 7 wtiles * 16 htiles * 4 batch
#define PLANE  (HH_*WW_)         // 28672

__global__ __launch_bounds__(64)
void corr_kernel(const float* __restrict__ first,
                 const float* __restrict__ second,
                 const float* __restrict__ zws,    // >=256 B of zeros in d_ws
                 float* __restrict__ out)
{
    const int bx   = blockIdx.x;
    const int tile = bx % NTILES;        // stride-448 dy-partners share XCD (448%8==0)
    const int dy   = bx / NTILES;        // 0..8
    const int wt   = tile % 7;
    const int ht   = (tile / 7) % 16;
    const int b    = tile / 112;
    const int w0   = wt * TW, h0 = ht * TH;

    const int lane = threadIdx.x;        // 0..63
    const int wq   = lane & 7;           // column quad
    const int hh   = lane >> 3;          // row within tile

    const int h = h0 + hh;
    const int w = w0 + 4 * wq;
    const int srow  = h + dy - PAD;
    const bool valid = (srow >= 0) && (srow < HH_);
    const int srowc = valid ? srow : 0;  // clamped for address arith only

    const size_t plane = PLANE;
    const float* fbase = first  + (size_t)b * CCH * plane;
    const float* sbase = second + (size_t)b * CCH * plane;

    const float* fp = fbase + (size_t)h * WW_ + w;
    const float* sp = valid ? (sbase + (size_t)srowc * WW_ + w) : zws;
    const size_t sinc = valid ? plane : 0;

    const bool isL = (wq == 0), isR = (wq == 7);
    const int  ecol   = isL ? (w0 - PAD) : (w0 + TW);
    const bool evalid = valid && ((isL && w0 > 0) || (isR && (w0 + TW) < WW_));
    const float* ep = evalid ? (sbase + (size_t)srowc * WW_ + ecol) : zws;
    const size_t einc = evalid ? plane : 0;

    const int li = (lane + 63) & 63;     // left neighbor
    const int ri = (lane + 1) & 63;      // right neighbor

    float acc[DD][4];
    #pragma unroll
    for (int dx = 0; dx < DD; ++dx) { acc[dx][0]=0.f; acc[dx][1]=0.f; acc[dx][2]=0.f; acc[dx][3]=0.f; }

    // prologue loads (channel 0)
    float4 f = *(const float4*)fp;  fp += plane;
    float4 m = *(const float4*)sp;  sp += sinc;
    float4 e = *(const float4*)ep;  ep += einc;

    for (int c = 0; c < CCH; ++c) {
        float4 fn, mn, en;
        if (c + 1 < CCH) {                       // prefetch next channel
            fn = *(const float4*)fp;  fp += plane;
            mn = *(const float4*)sp;  sp += sinc;
            en = *(const float4*)ep;  ep += einc;
        } else { fn = f; mn = m; en = e; }

        // halo quads via cross-lane shuffle (no LDS tile, no barrier)
        float a0 = __shfl(m.x, li), a1 = __shfl(m.y, li),
              a2 = __shfl(m.z, li), a3 = __shfl(m.w, li);
        float c0 = __shfl(m.x, ri), c1 = __shfl(m.y, ri),
              c2 = __shfl(m.z, ri), c3 = __shfl(m.w, ri);
        if (isL) { a0 = e.x; a1 = e.y; a2 = e.z; a3 = e.w; }
        if (isR) { c0 = e.x; c1 = e.y; c2 = e.z; c3 = e.w; }

        const float s[12] = { a0, a1, a2, a3,
                              m.x, m.y, m.z, m.w,
                              c0, c1, c2, c3 };
        const float fv[4] = { f.x, f.y, f.z, f.w };

        #pragma unroll
        for (int dx = 0; dx < DD; ++dx)
            #pragma unroll
            for (int px = 0; px < 4; ++px)
                acc[dx][px] += fv[px] * s[dx + px];

        f = fn; m = mn; e = en;
    }

    const float inv = 1.0f / (float)CCH;
    #pragma unroll
    for (int dx = 0; dx < DD; ++dx) {
        const int d = dy * DD + dx;
        float4 o = make_float4(acc[dx][0]*inv, acc[dx][1]*inv,
                               acc[dx][2]*inv, acc[dx][3]*inv);
        *(float4*)&out[(((size_t)b * ND + d) * HH_ + h) * WW_ + w] = o;
    }
}

extern "C" void kernel_launch(void* const* d_in, const int* in_sizes, int n_in,
                              void* d_out, int out_size, void* d_ws, size_t ws_size,
                              hipStream_t stream) {
    const float* first  = (const float*)d_in[0];
    const float* second = (const float*)d_in[1];
    float* out = (float*)d_out;
    // 256-B zero pad for all out-of-bounds pointer redirection (branchless halo)
    hipMemsetAsync(d_ws, 0, 256, stream);
    dim3 grid(NTILES * DD);   // 4032 single-wave blocks
    dim3 block(64);
    corr_kernel<<<grid, block, 0, stream>>>(first, second, (const float*)d_ws, out);
}